// Round 2
// baseline (207.309 us; speedup 1.0000x reference)
//
#include <hip/hip_runtime.h>

// FastAttention (Performer-style, causal) on MI355X. ALL fp32 (per reference).
// B=2, S=1024, D_MODEL=512, H=8, DEPTH=64, NFEAT=64.
// Pipeline:
//  kproj:     q/k/v per-head linear + ORF feature map (phi_q, phi_k, v') -> ws
//  kchunksum: per (bh, chunk of 64): sum_k phi_k [F], sum phi_k (x) v' [F,D]
//  kprefix:   exclusive prefix over the 16 chunks per (bh)
//  kattn:     per chunk: qn = phi_q / kcum; A = tril(qn @ k^T); O = A@v + qn@P
//  kfc:       [2048,512] @ Wfc^T + bfc -> fp32 out

#define BB 2
#define SS 1024
#define HH 8
#define DD 64
#define FF 64
#define DM 512
#define CH 64
#define NCH 16   // SS / CH

// ---------------- Kernel A: projection + feature map ----------------
// grid = B*H*(S/16)*3, block = 256. task 0=q,1=k,2=v.
__global__ __launch_bounds__(256) void kproj(
    const float* __restrict__ q_in, const float* __restrict__ k_in,
    const float* __restrict__ v_in,
    const float* __restrict__ Wq, const float* __restrict__ bq,
    const float* __restrict__ Wk, const float* __restrict__ bk,
    const float* __restrict__ Wv, const float* __restrict__ bv,
    const float* __restrict__ orf_q, const float* __restrict__ orf_k,
    float* __restrict__ PHI_Q, float* __restrict__ PHI_K, float* __restrict__ VP)
{
    __shared__ float Wl[64*65];   // stride 65: breaks 64-way bank conflict on row reads
    __shared__ float Ol[64*65];
    __shared__ float bias[64];
    __shared__ float xr[16*64];
    __shared__ float pr[16*64];

    const int tid = threadIdx.x;
    const int bid = blockIdx.x;
    const int task = bid % 3;
    const int tmp  = bid / 3;
    const int tile = tmp & 63;      // 64 tiles of 16 rows
    const int bh   = tmp >> 6;      // 0..15
    const int b    = bh >> 3, h = bh & 7;

    const float* X   = (task==0) ? q_in : (task==1) ? k_in : v_in;
    const float* W   = (task==0) ? Wq   : (task==1) ? Wk   : Wv;
    const float* bw  = (task==0) ? bq   : (task==1) ? bk   : bv;
    const float* orf = (task==0) ? orf_q : orf_k;

    #pragma unroll
    for (int i = 0; i < 16; i++) {
        int idx = i*256 + tid; int e = idx >> 6, d = idx & 63;
        Wl[e*65 + d] = W[idx];
        if (task < 2) Ol[e*65 + d] = orf[idx];
    }
    if (tid < 64) bias[tid] = bw[tid];
    #pragma unroll
    for (int i = 0; i < 4; i++) {
        int idx = i*256 + tid; int si = idx >> 6, d = idx & 63;
        int s = tile*16 + si;
        xr[idx] = X[(size_t)(b*SS + s)*DM + h*DD + d];
    }
    __syncthreads();

    float acc[4];
    #pragma unroll
    for (int i = 0; i < 4; i++) {
        int idx = i*256 + tid; int si = idx >> 6, e = idx & 63;
        float a = bias[e];
        #pragma unroll
        for (int d = 0; d < 64; d++) a += xr[si*64 + d] * Wl[e*65 + d];
        acc[i] = a;
    }

    if (task == 2) {
        #pragma unroll
        for (int i = 0; i < 4; i++) {
            int idx = i*256 + tid; int si = idx >> 6, e = idx & 63;
            int s = tile*16 + si;
            VP[((size_t)bh*SS + s)*DD + e] = acc[i];
        }
        return; // block-uniform early exit
    }

    #pragma unroll
    for (int i = 0; i < 4; i++) {
        int idx = i*256 + tid; int si = idx >> 6, e = idx & 63;
        pr[si*64 + e] = acc[i];
    }
    __syncthreads();

    float* PHI = (task == 0) ? PHI_Q : PHI_K;
    const float norm = 0.35355339059327373f; // 64^-0.25
    #pragma unroll
    for (int i = 0; i < 4; i++) {
        int idx = i*256 + tid; int si = idx >> 6, f = idx & 63;
        float a = 0.f;
        #pragma unroll
        for (int e = 0; e < 64; e++) a += pr[si*64 + e] * Ol[f*65 + e];
        a = norm * a;
        a = (a > 0.f) ? a : 0.f;
        a += 0.001f;
        int s = tile*16 + si;
        PHI[((size_t)bh*SS + s)*FF + f] = a;
    }
}

// ---------------- Kernel B1: per-chunk sums ----------------
// grid = BH*NCH = 256, block = 256. bid = bh*16 + c (chunks tile contiguously).
__global__ __launch_bounds__(256) void kchunksum(
    const float* __restrict__ PHI_K, const float* __restrict__ VP,
    float* __restrict__ CS, float* __restrict__ KCS)
{
    __shared__ float lk[4096];
    __shared__ float lv[4096];
    const int tid = threadIdx.x, bid = blockIdx.x;
    const size_t base = (size_t)bid * 4096; // == (bh*S + c*64)*64

    #pragma unroll
    for (int i = 0; i < 16; i++) {
        int idx = i*256 + tid;
        lk[idx] = PHI_K[base + idx];
        lv[idx] = VP[base + idx];
    }
    __syncthreads();

    const int f = tid >> 2, db = (tid & 3) * 16;
    float acc[16];
    #pragma unroll
    for (int j = 0; j < 16; j++) acc[j] = 0.f;

    for (int s = 0; s < 64; s++) {
        float kv = lk[s*64 + f];
        const float4* lv4 = (const float4*)&lv[s*64 + db];
        #pragma unroll
        for (int k = 0; k < 4; k++) {
            float4 vv = lv4[k];
            acc[k*4+0] += kv * vv.x; acc[k*4+1] += kv * vv.y;
            acc[k*4+2] += kv * vv.z; acc[k*4+3] += kv * vv.w;
        }
    }
    float* cs = CS + base + f*64 + db;
    #pragma unroll
    for (int k = 0; k < 4; k++)
        *(float4*)(cs + k*4) = make_float4(acc[k*4+0], acc[k*4+1], acc[k*4+2], acc[k*4+3]);

    if (tid < 64) {
        float kc = 0.f;
        for (int s = 0; s < 64; s++) kc += lk[s*64 + tid];
        KCS[(size_t)bid*64 + tid] = kc;
    }
}

// ---------------- Kernel B2: exclusive prefix over chunks ----------------
// grid = BH = 16, block = 256.
__global__ __launch_bounds__(256) void kprefix(float* __restrict__ CS, float* __restrict__ KCS)
{
    const int tid = threadIdx.x, bh = blockIdx.x;
    if (tid < 64) {
        float run = 0.f;
        for (int c = 0; c < NCH; c++) {
            size_t off = ((size_t)(bh*NCH + c))*64 + tid;
            float t = KCS[off]; KCS[off] = run; run += t;
        }
    }
    float run[16];
    #pragma unroll
    for (int i = 0; i < 16; i++) run[i] = 0.f;
    for (int c = 0; c < NCH; c++) {
        size_t cbase = ((size_t)(bh*NCH + c)) * 4096;
        #pragma unroll
        for (int i = 0; i < 16; i++) {
            int idx = i*256 + tid;
            float t = CS[cbase + idx]; CS[cbase + idx] = run[i]; run[i] += t;
        }
    }
}

// ---------------- Kernel C: per-chunk causal output ----------------
// grid = BH*NCH = 256, block = 256.
__global__ __launch_bounds__(256) void kattn(
    const float* __restrict__ PHI_Q, const float* __restrict__ PHI_K,
    const float* __restrict__ VP, const float* __restrict__ CS,
    const float* __restrict__ KCS, float* __restrict__ O)
{
    __shared__ float lq[4096];    // phi_q, becomes qn in place
    __shared__ float lk[64*65];   // phi_k (stride 65), later reused as A (stride 64)
    __shared__ float lv[4096];
    const int tid = threadIdx.x, bid = blockIdx.x;
    const size_t base = (size_t)bid * 4096;

    #pragma unroll
    for (int i = 0; i < 16; i++) {
        int idx = i*256 + tid; int s = idx >> 6, f = idx & 63;
        lq[idx]        = PHI_Q[base + idx];
        lk[s*65 + f]   = PHI_K[base + idx];
        lv[idx]        = VP[base + idx];
    }
    __syncthreads();

    // cumulative k-sum + qn = phi_q / kcum (inclusive, seeded with chunk prefix)
    if (tid < 64) {
        const int f = tid;
        float run = KCS[(size_t)bid*64 + f];
        for (int s = 0; s < 64; s++) {
            run += lk[s*65 + f];
            lq[s*64 + f] = lq[s*64 + f] / run;
        }
    }
    __syncthreads();

    // A[s][t] = (t<=s) ? sum_f qn[s,f]*k[t,f] : 0
    float a[16];
    {
        const int t = tid & 63, shi = tid >> 6;
        #pragma unroll
        for (int i = 0; i < 16; i++) {
            int s = i*4 + shi;
            float acc = 0.f;
            if (t <= s) {
                #pragma unroll
                for (int f = 0; f < 64; f++) acc += lq[s*64 + f] * lk[t*65 + f];
            }
            a[i] = acc;
        }
    }
    __syncthreads();
    {
        const int t = tid & 63, shi = tid >> 6;
        #pragma unroll
        for (int i = 0; i < 16; i++) { int s = i*4 + shi; lk[s*64 + t] = a[i]; }
    }
    __syncthreads();

    // O[s][d] = sum_t A[s][t]*v[t][d] + sum_f qn[s][f]*P[f][d]
    {
        const int d = tid & 63, g = tid >> 6;
        float o[16];
        #pragma unroll
        for (int j = 0; j < 16; j++) o[j] = 0.f;

        for (int t = 0; t < 64; t++) {
            float lvv = lv[t*64 + d];
            #pragma unroll
            for (int j = 0; j < 16; j++) { int s = g*16 + j; o[j] += lk[s*64 + t] * lvv; }
        }
        const float* P = CS + base; // exclusive prefix state [F,D]
        for (int f = 0; f < 64; f++) {
            float pv = P[f*64 + d];
            #pragma unroll
            for (int j = 0; j < 16; j++) { int s = g*16 + j; o[j] += lq[s*64 + f] * pv; }
        }
        #pragma unroll
        for (int j = 0; j < 16; j++) {
            int s = g*16 + j;
            O[base + (size_t)s*64 + d] = o[j];
        }
    }
}

// ---------------- Kernel D: output FC ----------------
// grid = B*(S/8) = 256, block = 256. Each block: 8 rows x 512 outputs.
__global__ __launch_bounds__(256) void kfc(
    const float* __restrict__ O, const float* __restrict__ Wfc,
    const float* __restrict__ bfc, float* __restrict__ out)
{
    __shared__ float xs[8*512];
    const int tid = threadIdx.x, bid = blockIdx.x;
    const int b = bid >> 7, stile = bid & 127;
    const int s0 = stile * 8;

    #pragma unroll
    for (int i = 0; i < 16; i++) {
        int idx = i*256 + tid; int r = idx >> 9, e = idx & 511;
        int s = s0 + r;
        xs[idx] = O[((size_t)(b*HH + (e >> 6))*SS + s)*DD + (e & 63)];
    }
    __syncthreads();

    const int o0 = tid, o1 = tid + 256;
    float acc0[8], acc1[8];
    const float bb0 = bfc[o0];
    const float bb1 = bfc[o1];
    #pragma unroll
    for (int r = 0; r < 8; r++) { acc0[r] = bb0; acc1[r] = bb1; }

    const float4* w0p = (const float4*)(Wfc + (size_t)o0 * DM);
    const float4* w1p = (const float4*)(Wfc + (size_t)o1 * DM);

    for (int eb = 0; eb < 64; eb++) {
        float4 wa0 = w0p[2*eb], wb0 = w0p[2*eb+1];
        float4 wa1 = w1p[2*eb], wb1 = w1p[2*eb+1];
        int e = eb * 8;
        #pragma unroll
        for (int r = 0; r < 8; r++) {
            const float4* xp = (const float4*)&xs[r*512 + e];
            float4 xa = xp[0], xb = xp[1];
            acc0[r] += xa.x*wa0.x + xa.y*wa0.y + xa.z*wa0.z + xa.w*wa0.w
                     + xb.x*wb0.x + xb.y*wb0.y + xb.z*wb0.z + xb.w*wb0.w;
            acc1[r] += xa.x*wa1.x + xa.y*wa1.y + xa.z*wa1.z + xa.w*wa1.w
                     + xb.x*wb1.x + xb.y*wb1.y + xb.z*wb1.z + xb.w*wb1.w;
        }
    }
    #pragma unroll
    for (int r = 0; r < 8; r++) {
        size_t row = ((size_t)b*SS + s0 + r) * DM;
        out[row + o0] = acc0[r];
        out[row + o1] = acc1[r];
    }
}

extern "C" void kernel_launch(void* const* d_in, const int* in_sizes, int n_in,
                              void* d_out, int out_size, void* d_ws, size_t ws_size,
                              hipStream_t stream) {
    const float* q_in  = (const float*)d_in[0];
    const float* k_in  = (const float*)d_in[1];
    const float* v_in  = (const float*)d_in[2];
    const float* Wq    = (const float*)d_in[3];
    const float* bq    = (const float*)d_in[4];
    const float* Wk    = (const float*)d_in[5];
    const float* bk    = (const float*)d_in[6];
    const float* Wv    = (const float*)d_in[7];
    const float* bv    = (const float*)d_in[8];
    const float* orf_q = (const float*)d_in[9];
    const float* orf_k = (const float*)d_in[10];
    const float* Wfc   = (const float*)d_in[11];
    const float* bfc   = (const float*)d_in[12];
    // d_in[13] = causal (int, always 1 for this dataset)

    float* ws    = (float*)d_ws;
    float* PHI_Q = ws;                 // 16*1024*64 = 1048576
    float* PHI_K = ws + 1048576;       // 1048576
    float* VP    = ws + 2097152;       // 1048576
    float* CS    = ws + 3145728;       // 256*4096 = 1048576 (chunk sums -> exclusive prefix)
    float* KCS   = ws + 4194304;       // 256*64 = 16384
    float* O     = ws + 4210688;       // 1048576
    // total 5259264 floats ~= 21 MB

    kproj<<<BB*HH*(SS/16)*3, 256, 0, stream>>>(q_in, k_in, v_in, Wq, bq, Wk, bk, Wv, bv,
                                               orf_q, orf_k, PHI_Q, PHI_K, VP);
    kchunksum<<<BB*HH*NCH, 256, 0, stream>>>(PHI_K, VP, CS, KCS);
    kprefix<<<BB*HH, 256, 0, stream>>>(CS, KCS);
    kattn<<<BB*HH*NCH, 256, 0, stream>>>(PHI_Q, PHI_K, VP, CS, KCS, O);
    kfc<<<BB*(SS/8), 256, 0, stream>>>(O, Wfc, bfc, (float*)d_out);
}